// Round 4
// baseline (211.834 us; speedup 1.0000x reference)
//
#include <hip/hip_runtime.h>
#include <hip/hip_bf16.h>
#include <hip/hip_fp16.h>

typedef _Float16 half8 __attribute__((ext_vector_type(8)));
typedef _Float16 half4 __attribute__((ext_vector_type(4)));
typedef _Float16 half2v __attribute__((ext_vector_type(2)));
typedef float f32x4 __attribute__((ext_vector_type(4)));

#define LN_EPS 1e-5f
#define MASK_FILL -1e9f

// async global->LDS, 16B per lane. LDS dest is wave-uniform base + lane*16.
__device__ __forceinline__ void async16(void* lds, const void* g) {
  __builtin_amdgcn_global_load_lds(
      (__attribute__((address_space(1))) void*)(g),
      (__attribute__((address_space(3))) void*)(lds), 16, 0, 0);
}

// ---------------- cast f32 -> f16 (vec4) ----------------
__global__ __launch_bounds__(256) void cast_f32_f16_kernel(
    const float* __restrict__ in, _Float16* __restrict__ out, int n4) {
  int i = blockIdx.x * 256 + threadIdx.x;
  if (i < n4) {
    float4 v = ((const float4*)in)[i];
    half4 h = { (_Float16)v.x, (_Float16)v.y, (_Float16)v.z, (_Float16)v.w };
    ((half4*)out)[i] = h;
  }
}

// ---------------- transpose f32 [R][C] -> f16 [C][R] ----------------
__global__ __launch_bounds__(256) void transpose_f32_to_f16_kernel(
    const float* __restrict__ in, _Float16* __restrict__ out, int R, int C) {
  __shared__ float tile[32][33];
  int bc = blockIdx.x * 32, br = blockIdx.y * 32;
  int lc = threadIdx.x & 31;
  int lr0 = threadIdx.x >> 5;  // 0..7
  for (int i = lr0; i < 32; i += 8)
    tile[i][lc] = in[(size_t)(br + i) * C + bc + lc];
  __syncthreads();
  for (int i = lr0; i < 32; i += 8)
    out[(size_t)(bc + i) * R + br + lc] = (_Float16)tile[lc][i];
}

// ---------------- prep: compact rows with dmask!=0 ----------------
// 1 block, 256 threads. Outputs: rowmap (compact->orig row), row_w (=1/nv(kd)),
// start[65] (per-kd compact range), keepM.
__global__ __launch_bounds__(256) void prep_kernel(
    const int* __restrict__ dmask, int* __restrict__ rowmap,
    float* __restrict__ row_w, int* __restrict__ start, int* __restrict__ keepM) {
  __shared__ int lsum[256];
  __shared__ int nvs[64];
  const int tid = threadIdx.x;
  int flags[8];
  int cnt = 0;
#pragma unroll
  for (int u = 0; u < 8; u++) {
    flags[u] = dmask[tid * 8 + u] != 0;
    cnt += flags[u];
  }
  if (tid < 64) {
    int c = 0;
    for (int u = 0; u < 32; u++) c += (dmask[tid * 32 + u] != 0);
    nvs[tid] = c;
  }
  lsum[tid] = cnt;
  __syncthreads();
  for (int ofs = 1; ofs < 256; ofs <<= 1) {
    int t = (tid >= ofs) ? lsum[tid - ofs] : 0;
    __syncthreads();
    lsum[tid] += t;
    __syncthreads();
  }
  int excl = lsum[tid] - cnt;
  int pos = excl;
#pragma unroll
  for (int u = 0; u < 8; u++) {
    if (flags[u]) {
      int row = tid * 8 + u;
      rowmap[pos] = row;
      row_w[pos] = 1.0f / (float)nvs[row >> 5];
      pos++;
    }
  }
  if ((tid & 3) == 0) start[tid >> 2] = excl;
  if (tid == 255) {
    start[64] = lsum[255];
    *keepM = lsum[255];
  }
}

// ---------------- gather kept rows of a [2048][768] f16 matrix ------------
// dst[r] = src[rowmap[r]] for r < keepM, else zeros (pad for GEMM tiles).
__global__ __launch_bounds__(256) void gather_rows_kernel(
    const _Float16* __restrict__ src, const int* __restrict__ rowmap,
    const int* __restrict__ keepM, _Float16* __restrict__ dst) {
  const int r = blockIdx.x;
  const int t = threadIdx.x;
  const int k = *keepM;
  int* d = (int*)(dst + (size_t)r * 768);
  if (r < k) {
    const int* s = (const int*)(src + (size_t)rowmap[r] * 768);
    for (int i = t; i < 384; i += 256) d[i] = s[i];
  } else {
    for (int i = t; i < 384; i += 256) d[i] = 0;
  }
}

// ---------------- fp16 MFMA GEMM, m97 structure, BK=64 ----------------
// C[M][N] = alpha * A[M][K] @ Bt[N][K]^T. 128x128 tile, BK=64, 4 waves (2x2),
// each wave 64x64 via 4x4 16x16x32 frags x2 k-subtiles. global_load_lds(16B)
// into LINEAR [128][64] LDS. Optional early-exit when bm >= *keepRows.
template<bool OUT_F32>
__global__ __launch_bounds__(256) void gemm_f16_kernel(
    const _Float16* __restrict__ A, const _Float16* __restrict__ Bt,
    void* __restrict__ C, int M, int N, int K, float alpha,
    size_t strideBt, size_t strideC, const int* __restrict__ keepRows) {
  const int bm = blockIdx.x * 128, bn = blockIdx.y * 128;
  if (keepRows && bm >= *keepRows) return;
  __shared__ _Float16 As[128 * 64];
  __shared__ _Float16 Bs[128 * 64];
  const int tid = threadIdx.x;
  const size_t z = blockIdx.z;
  const int wave = tid >> 6, lane = tid & 63;
  const int wr = (wave >> 1) * 64, wc = (wave & 1) * 64;
  const int fr = lane & 15, kg = (lane >> 4) * 8;
  f32x4 acc[4][4] = {};
  // staging: wave w covers rows [w*32, w*32+32); one issue = 8 rows of 128B.
  const int srow = wave * 32 + (lane >> 3);
  const int scol = (lane & 7) * 8;
  const _Float16* ga = A + (size_t)(bm + srow) * K + scol;
  const _Float16* gb = Bt + z * strideBt + (size_t)(bn + srow) * K + scol;
  _Float16* lA = &As[(wave * 32) * 64];
  _Float16* lB = &Bs[(wave * 32) * 64];
  for (int k0 = 0; k0 < K; k0 += 64) {
    __syncthreads();  // all waves done reading LDS from previous iter
#pragma unroll
    for (int i = 0; i < 4; i++) {
      async16(lA + i * 8 * 64, ga + (size_t)(8 * i) * K + k0);
      async16(lB + i * 8 * 64, gb + (size_t)(8 * i) * K + k0);
    }
    __syncthreads();  // drains vmcnt(0): staging complete
#pragma unroll
    for (int k2 = 0; k2 < 2; k2++) {
      half8 af[4], bf[4];
#pragma unroll
      for (int i = 0; i < 4; i++)
        af[i] = *(const half8*)&As[(wr + i * 16 + fr) * 64 + k2 * 32 + kg];
#pragma unroll
      for (int j = 0; j < 4; j++)
        bf[j] = *(const half8*)&Bs[(wc + j * 16 + fr) * 64 + k2 * 32 + kg];
#pragma unroll
      for (int i = 0; i < 4; i++)
#pragma unroll
        for (int j = 0; j < 4; j++)
          acc[i][j] = __builtin_amdgcn_mfma_f32_16x16x32_f16(af[i], bf[j], acc[i][j], 0, 0, 0);
    }
  }
  const int rg = (lane >> 4) * 4;
#pragma unroll
  for (int i = 0; i < 4; i++) {
#pragma unroll
    for (int j = 0; j < 4; j++) {
      int col = bn + wc + j * 16 + fr;
#pragma unroll
      for (int r = 0; r < 4; r++) {
        int row = bm + wr + i * 16 + rg + r;
        float v = acc[i][j][r] * alpha;
        if (OUT_F32)
          ((float*)C)[z * strideC + (size_t)row * N + col] = v;
        else
          ((_Float16*)C)[z * strideC + (size_t)row * N + col] = (_Float16)v;
      }
    }
  }
}

// ---------------- block reduce helper (256 threads, 4 waves) ----------------
__device__ __forceinline__ float block_reduce(float v, bool do_max, float* wbuf, int tid) {
#pragma unroll
  for (int m = 32; m; m >>= 1) {
    float o = __shfl_xor(v, m);
    v = do_max ? fmaxf(v, o) : (v + o);
  }
  if ((tid & 63) == 0) wbuf[tid >> 6] = v;
  __syncthreads();
  float r = do_max ? fmaxf(fmaxf(wbuf[0], wbuf[1]), fmaxf(wbuf[2], wbuf[3]))
                   : (wbuf[0] + wbuf[1] + wbuf[2] + wbuf[3]);
  __syncthreads();
  return r;
}

// ---------------- pass 1: per-compact-row masked softmax stats -------------
// One block per kept S-row. stats_c[b*2048+r] = (rowmax, w/denom, 0, 0)
__global__ __launch_bounds__(256) void row_stats_kernel(
    const _Float16* __restrict__ S, const float* __restrict__ row_w,
    const int* __restrict__ keepM, const int* __restrict__ amask,
    float4* __restrict__ stats_c) {
  const int r = blockIdx.x;
  if (r >= *keepM) return;
  __shared__ float wbuf[4];
  const int b = blockIdx.z;
  const int tid = threadIdx.x;
  const float w = row_w[r];
  const _Float16* sp = S + ((size_t)b * 2048 + r) * 4096;
  const int* am = amask + (size_t)b * 4096;
  float a[16];
#pragma unroll
  for (int h = 0; h < 2; h++) {
    half8 v = *(const half8*)(sp + h * 2048 + tid * 8);
    int4 m0 = *(const int4*)(am + h * 2048 + tid * 8);
    int4 m1 = *(const int4*)(am + h * 2048 + tid * 8 + 4);
    int mm[8] = {m0.x, m0.y, m0.z, m0.w, m1.x, m1.y, m1.z, m1.w};
#pragma unroll
    for (int u = 0; u < 8; u++)
      a[h * 8 + u] = (mm[u] != 0) ? (float)v[u] : MASK_FILL;
  }
  float mx = a[0];
#pragma unroll
  for (int c = 1; c < 16; c++) mx = fmaxf(mx, a[c]);
  mx = block_reduce(mx, true, wbuf, tid);
  float ls = 0.f;
#pragma unroll
  for (int c = 0; c < 16; c++) ls += expf(a[c] - mx);
  float denom = block_reduce(ls, false, wbuf, tid);
  if (tid == 0)
    stats_c[(size_t)b * 2048 + r] = make_float4(mx, w / denom, 0.f, 0.f);
}

// ---------------- pass 2: ds-weighted combine over kept rows ---------------
// ca[b][kd][n] = sum_{i in [start[kd],start[kd+1])} iw * exp(a - mx)
// cnt==0 (nv==0 corner): uniform 1/4096.
__global__ __launch_bounds__(256) void combine_kernel(
    const _Float16* __restrict__ S, const float4* __restrict__ stats_c,
    const int* __restrict__ start, const int* __restrict__ amask,
    float* __restrict__ ca) {
  const int kd = blockIdx.x;
  const int b = blockIdx.z;
  const int n0 = blockIdx.y * 512 + threadIdx.x * 2;
  const int i0 = start[kd], i1 = start[kd + 1];
  float acc0, acc1;
  if (i0 == i1) {
    acc0 = acc1 = 1.0f / 4096.0f;
  } else {
    const int* am = amask + (size_t)b * 4096;
    const bool nm0 = am[n0] != 0, nm1 = am[n0 + 1] != 0;
    acc0 = 0.f;
    acc1 = 0.f;
    for (int i = i0; i < i1; i++) {
      float4 s4 = stats_c[(size_t)b * 2048 + i];
      half2v v = *(const half2v*)(S + ((size_t)b * 2048 + i) * 4096 + n0);
      float a0 = nm0 ? (float)v[0] : MASK_FILL;
      float a1 = nm1 ? (float)v[1] : MASK_FILL;
      acc0 += s4.y * expf(a0 - s4.x);
      acc1 += s4.y * expf(a1 - s4.x);
    }
  }
  float2 r = {acc0, acc1};
  *(float2*)&ca[((size_t)b * 64 + kd) * 4096 + n0] = r;
}

// ---------------- t partial: t[b*64+m][j] = sum_n ca[b][m][n] * x[b][n][j] ----
__global__ __launch_bounds__(256) void t_partial_kernel(
    const float* __restrict__ ca,   // [4][64][4096]
    const float* __restrict__ x,    // [4][4096][768]
    float* __restrict__ t_part) {   // [16][256][768]
  __shared__ float cas[64][68];
  __shared__ float xs[64][68];
  const int jt = blockIdx.x;  // 0..11
  const int nc = blockIdx.y;  // 0..15
  const int b = blockIdx.z;   // 0..3
  const int tid = threadIdx.x;
  const int tm = tid >> 4, tj = tid & 15;
  const int r = tid >> 2, cg = (tid & 3) * 16;
  float acc[4][4] = {};
  for (int n0 = nc * 256; n0 < nc * 256 + 256; n0 += 64) {
    __syncthreads();
    const float* cap = ca + ((size_t)(b * 64 + r)) * 4096 + n0 + cg;
    const float* xp = x + ((size_t)b * 4096 + n0 + r) * 768 + jt * 64 + cg;
#pragma unroll
    for (int u = 0; u < 16; u += 4) {
      *(float4*)&cas[r][cg + u] = *(const float4*)(cap + u);
      *(float4*)&xs[r][cg + u] = *(const float4*)(xp + u);
    }
    __syncthreads();
#pragma unroll 16
    for (int nn = 0; nn < 64; ++nn) {
      float cm[4], xj[4];
#pragma unroll
      for (int i = 0; i < 4; i++) cm[i] = cas[tm * 4 + i][nn];
#pragma unroll
      for (int j = 0; j < 4; j++) xj[j] = xs[nn][tj * 4 + j];
#pragma unroll
      for (int i = 0; i < 4; i++)
#pragma unroll
        for (int j = 0; j < 4; j++) acc[i][j] += cm[i] * xj[j];
    }
  }
#pragma unroll
  for (int i = 0; i < 4; i++)
#pragma unroll
    for (int j = 0; j < 4; j++)
      t_part[((size_t)nc * 256 + b * 64 + tm * 4 + i) * 768 + jt * 64 + tj * 4 + j] = acc[i][j];
}

__global__ __launch_bounds__(256) void t_reduce_kernel(
    const float* __restrict__ t_part, float* __restrict__ t) {
  int i = blockIdx.x * 256 + threadIdx.x;  // < 196608
  float s = 0.f;
#pragma unroll
  for (int nc = 0; nc < 16; ++nc) s += t_part[(size_t)nc * 196608 + i];
  t[i] = s;
}

// ---------------- LayerNorm + final projection ----------------
__global__ __launch_bounds__(256) void ln_out_kernel(
    const float* __restrict__ pooled, const float* __restrict__ Wo,
    const float* __restrict__ bo, const float* __restrict__ gamma,
    const float* __restrict__ beta, float* __restrict__ out) {
  __shared__ float wbuf[4];
  const int row = blockIdx.x, tid = threadIdx.x;
  float p[3];
#pragma unroll
  for (int u = 0; u < 3; u++) p[u] = pooled[(size_t)row * 768 + tid + u * 256];
  float s1 = p[0] + p[1] + p[2];
  float s2 = p[0] * p[0] + p[1] * p[1] + p[2] * p[2];
  s1 = block_reduce(s1, false, wbuf, tid);
  s2 = block_reduce(s2, false, wbuf, tid);
  float mean = s1 * (1.f / 768.f);
  float var = s2 * (1.f / 768.f) - mean * mean;
  float rstd = rsqrtf(var + LN_EPS);
  float accv = 0.f;
#pragma unroll
  for (int u = 0; u < 3; u++) {
    int i = tid + u * 256;
    float y = (p[u] - mean) * rstd * gamma[i] + beta[i];
    accv += y * Wo[i];
  }
  accv = block_reduce(accv, false, wbuf, tid);
  if (tid == 0) out[row] = accv + bo[0];
}

extern "C" void kernel_launch(void* const* d_in, const int* in_sizes, int n_in,
                              void* d_out, int out_size, void* d_ws, size_t ws_size,
                              hipStream_t stream) {
  const float* x = (const float*)d_in[0];
  const float* enc = (const float*)d_in[1];
  const int* dmask = (const int*)d_in[2];
  const int* amask = (const int*)d_in[3];
  const float* Wk = (const float*)d_in[4];
  const float* Wv = (const float*)d_in[5];
  const float* Wo = (const float*)d_in[6];
  const float* bo = (const float*)d_in[7];
  const float* gamma = (const float*)d_in[8];
  const float* beta = (const float*)d_in[9];
  float* out = (float*)d_out;

  char* ws = (char*)d_ws;
  size_t off = 0;
  auto alloc = [&](size_t bytes) -> char* {
    char* p = ws + off;
    off += (bytes + 255) & ~((size_t)255);
    return p;
  };
  _Float16* xh = (_Float16*)alloc((size_t)16384 * 768 * 2);
  _Float16* ench = (_Float16*)alloc((size_t)2048 * 768 * 2);
  _Float16* wkT = (_Float16*)alloc((size_t)768 * 768 * 2);
  _Float16* wvh = (_Float16*)alloc((size_t)768 * 768 * 2);
  _Float16* enc_c = (_Float16*)alloc((size_t)2048 * 768 * 2);
  _Float16* encK_c = (_Float16*)alloc((size_t)2048 * 768 * 2);
  float* ca = (float*)alloc((size_t)4 * 64 * 4096 * 4);
  float* t_part = (float*)alloc((size_t)16 * 256 * 768 * 4);
  float* t = (float*)alloc((size_t)256 * 768 * 4);
  _Float16* th = (_Float16*)alloc((size_t)256 * 768 * 2);
  float* pooled = (float*)alloc((size_t)256 * 768 * 4);
  float4* stats_c = (float4*)alloc((size_t)4 * 2048 * 16);
  int* rowmap = (int*)alloc(2048 * 4);
  float* row_w = (float*)alloc(2048 * 4);
  int* start = (int*)alloc(65 * 4);
  int* keepM = (int*)alloc(4);

  // batched path needs 4 S buffers (67.1 MB); fallback needs 1 (16.8 MB)
  const size_t s_one = (size_t)2048 * 4096 * 2;
  const bool batched = (off + 4 * s_one) <= ws_size;
  _Float16* S = (_Float16*)alloc(batched ? 4 * s_one : s_one);

  const float scale = 0.036084391824351615f;  // 1/sqrt(768)

  prep_kernel<<<1, 256, 0, stream>>>(dmask, rowmap, row_w, start, keepM);
  cast_f32_f16_kernel<<<12288, 256, 0, stream>>>(x, xh, 16384 * 768 / 4);
  cast_f32_f16_kernel<<<1536, 256, 0, stream>>>(enc, ench, 2048 * 768 / 4);
  cast_f32_f16_kernel<<<576, 256, 0, stream>>>(Wv, wvh, 768 * 768 / 4);
  transpose_f32_to_f16_kernel<<<dim3(24, 24), 256, 0, stream>>>(Wk, wkT, 768, 768);
  gather_rows_kernel<<<2048, 256, 0, stream>>>(ench, rowmap, keepM, enc_c);

  // encK_c = enc_c @ Wk   [keepM x 768]
  gemm_f16_kernel<false><<<dim3(16, 6), 256, 0, stream>>>(
      enc_c, wkT, encK_c, 2048, 768, 768, 1.0f, 0, 0, keepM);

  if (batched) {
    gemm_f16_kernel<false><<<dim3(16, 32, 4), 256, 0, stream>>>(
        encK_c, xh, S, 2048, 4096, 768, scale,
        (size_t)4096 * 768, (size_t)2048 * 4096, keepM);
    row_stats_kernel<<<dim3(2048, 1, 4), 256, 0, stream>>>(
        S, row_w, keepM, amask, stats_c);
    combine_kernel<<<dim3(64, 8, 4), 256, 0, stream>>>(S, stats_c, start, amask, ca);
  } else {
    for (int b = 0; b < 4; b++) {
      gemm_f16_kernel<false><<<dim3(16, 32), 256, 0, stream>>>(
          encK_c, xh + (size_t)b * 4096 * 768, S, 2048, 4096, 768, scale, 0, 0, keepM);
      row_stats_kernel<<<dim3(2048, 1, 1), 256, 0, stream>>>(
          S, row_w, keepM, amask + (size_t)b * 4096, stats_c + (size_t)b * 2048);
      // note: per-batch kernels use b=blockIdx.z=0; stats_c offset passed via pointer,
      // amask offset via pointer; combine likewise.
      combine_kernel<<<dim3(64, 8, 1), 256, 0, stream>>>(
          S, stats_c + (size_t)b * 2048, start, amask + (size_t)b * 4096,
          ca + (size_t)b * 64 * 4096);
    }
  }

  // t = ca @ x  (fp32), split over n-chunks then reduced
  t_partial_kernel<<<dim3(12, 16, 4), 256, 0, stream>>>(ca, x, t_part);
  t_reduce_kernel<<<768, 256, 0, stream>>>(t_part, t);
  cast_f32_f16_kernel<<<192, 256, 0, stream>>>(t, th, 196608 / 4);
  // pooled = t @ Wv^T  [256 x 768] fp32
  gemm_f16_kernel<true><<<dim3(2, 6), 256, 0, stream>>>(
      th, wvh, pooled, 256, 768, 768, 1.0f, 0, 0, nullptr);
  ln_out_kernel<<<256, 256, 0, stream>>>(pooled, Wo, bo, gamma, beta, out);
}

// Round 5
// 181.939 us; speedup vs baseline: 1.1643x; 1.1643x over previous
//
#include <hip/hip_runtime.h>
#include <hip/hip_bf16.h>
#include <hip/hip_fp16.h>

typedef _Float16 half8 __attribute__((ext_vector_type(8)));
typedef _Float16 half4 __attribute__((ext_vector_type(4)));
typedef _Float16 half2v __attribute__((ext_vector_type(2)));
typedef float f32x4 __attribute__((ext_vector_type(4)));

#define LN_EPS 1e-5f
#define MASK_FILL -1e9f

// async global->LDS, 16B per lane. LDS dest is wave-uniform base + lane*16.
__device__ __forceinline__ void async16(void* lds, const void* g) {
  __builtin_amdgcn_global_load_lds(
      (__attribute__((address_space(1))) void*)(g),
      (__attribute__((address_space(3))) void*)(lds), 16, 0, 0);
}

// ---------------- cast f32 -> f16 (vec4) ----------------
__global__ __launch_bounds__(256) void cast_f32_f16_kernel(
    const float* __restrict__ in, _Float16* __restrict__ out, int n4) {
  int i = blockIdx.x * 256 + threadIdx.x;
  if (i < n4) {
    float4 v = ((const float4*)in)[i];
    half4 h = { (_Float16)v.x, (_Float16)v.y, (_Float16)v.z, (_Float16)v.w };
    ((half4*)out)[i] = h;
  }
}

// ---------------- transpose f32 [R][C] -> f16 [C][R] ----------------
__global__ __launch_bounds__(256) void transpose_f32_to_f16_kernel(
    const float* __restrict__ in, _Float16* __restrict__ out, int R, int C) {
  __shared__ float tile[32][33];
  int bc = blockIdx.x * 32, br = blockIdx.y * 32;
  int lc = threadIdx.x & 31;
  int lr0 = threadIdx.x >> 5;  // 0..7
  for (int i = lr0; i < 32; i += 8)
    tile[i][lc] = in[(size_t)(br + i) * C + bc + lc];
  __syncthreads();
  for (int i = lr0; i < 32; i += 8)
    out[(size_t)(bc + i) * R + br + lc] = (_Float16)tile[lc][i];
}

// ---------------- prep: compact rows with dmask!=0 ----------------
// 1 block, 256 threads. Outputs: rowmap (compact->orig row), row_w (=1/nv(kd)),
// start[65] (per-kd compact range), keepM.
__global__ __launch_bounds__(256) void prep_kernel(
    const int* __restrict__ dmask, int* __restrict__ rowmap,
    float* __restrict__ row_w, int* __restrict__ start, int* __restrict__ keepM) {
  __shared__ int lsum[256];
  __shared__ int nvs[64];
  const int tid = threadIdx.x;
  int flags[8];
  int cnt = 0;
#pragma unroll
  for (int u = 0; u < 8; u++) {
    flags[u] = dmask[tid * 8 + u] != 0;
    cnt += flags[u];
  }
  if (tid < 64) {
    int c = 0;
    for (int u = 0; u < 32; u++) c += (dmask[tid * 32 + u] != 0);
    nvs[tid] = c;
  }
  lsum[tid] = cnt;
  __syncthreads();
  for (int ofs = 1; ofs < 256; ofs <<= 1) {
    int t = (tid >= ofs) ? lsum[tid - ofs] : 0;
    __syncthreads();
    lsum[tid] += t;
    __syncthreads();
  }
  int excl = lsum[tid] - cnt;
  int pos = excl;
#pragma unroll
  for (int u = 0; u < 8; u++) {
    if (flags[u]) {
      int row = tid * 8 + u;
      rowmap[pos] = row;
      row_w[pos] = 1.0f / (float)nvs[row >> 5];
      pos++;
    }
  }
  if ((tid & 3) == 0) start[tid >> 2] = excl;
  if (tid == 255) {
    start[64] = lsum[255];
    *keepM = lsum[255];
  }
}

// ---------------- gather kept rows of a [2048][768] f16 matrix ------------
// dst[r] = src[rowmap[r]] for r < keepM, else zeros (pad for GEMM tiles).
__global__ __launch_bounds__(256) void gather_rows_kernel(
    const _Float16* __restrict__ src, const int* __restrict__ rowmap,
    const int* __restrict__ keepM, _Float16* __restrict__ dst) {
  const int r = blockIdx.x;
  const int t = threadIdx.x;
  const int k = *keepM;
  int* d = (int*)(dst + (size_t)r * 768);
  if (r < k) {
    const int* s = (const int*)(src + (size_t)rowmap[r] * 768);
    for (int i = t; i < 384; i += 256) d[i] = s[i];
  } else {
    for (int i = t; i < 384; i += 256) d[i] = 0;
  }
}

// ---------------- fp16 MFMA GEMM, m97 structure, BK=64, XOR-swizzled LDS ---
// C[M][N] = alpha * A[M][K] @ Bt[N][K]^T. 128x128 tile, BK=64, 4 waves (2x2),
// each wave 64x64 via 4x4 16x16x32 frags x2 k-subtiles.
// LDS layout: LDS[row][slot] = orig[row][slot ^ (row&7)] (16B granules, 8/row).
// Achieved by pre-swizzling the per-lane GLOBAL src (LDS dest stays linear,
// as global_load_lds requires); ds_reads XOR the slot with (row&7) -> 2-way
// bank access (free) instead of 16-way.
template<bool OUT_F32>
__global__ __launch_bounds__(256) void gemm_f16_kernel(
    const _Float16* __restrict__ A, const _Float16* __restrict__ Bt,
    void* __restrict__ C, int M, int N, int K, float alpha,
    size_t strideBt, size_t strideC, const int* __restrict__ keepRows) {
  const int bm = blockIdx.x * 128, bn = blockIdx.y * 128;
  if (keepRows && bm >= *keepRows) return;
  __shared__ _Float16 As[128 * 64];
  __shared__ _Float16 Bs[128 * 64];
  const int tid = threadIdx.x;
  const size_t z = blockIdx.z;
  const int wave = tid >> 6, lane = tid & 63;
  const int wr = (wave >> 1) * 64, wc = (wave & 1) * 64;
  const int fr = lane & 15, xr = lane & 7;  // xr = (frag row)&7 for all i,j
  f32x4 acc[4][4] = {};
  // staging: wave w covers rows [w*32, w*32+32); one issue = 8 rows of 128B.
  // lane l -> row (l>>3), LDS slot (l&7); global granule = (l&7)^(l>>3)
  // (row&7 == l>>3 since issue/wave offsets are multiples of 8).
  const int srow = wave * 32 + (lane >> 3);
  const int scol = (((lane & 7) ^ (lane >> 3))) * 8;  // elems
  const _Float16* ga = A + (size_t)(bm + srow) * K + scol;
  const _Float16* gb = Bt + z * strideBt + (size_t)(bn + srow) * K + scol;
  _Float16* lA = &As[(wave * 32) * 64];
  _Float16* lB = &Bs[(wave * 32) * 64];
  for (int k0 = 0; k0 < K; k0 += 64) {
    __syncthreads();  // all waves done reading LDS from previous iter
#pragma unroll
    for (int i = 0; i < 4; i++) {
      async16(lA + i * 8 * 64, ga + (size_t)(8 * i) * K + k0);
      async16(lB + i * 8 * 64, gb + (size_t)(8 * i) * K + k0);
    }
    __syncthreads();  // drains vmcnt(0): staging complete
#pragma unroll
    for (int k2 = 0; k2 < 2; k2++) {
      const int sb = k2 * 4 + (lane >> 4);  // unswizzled slot this lane needs
      const int so = (sb ^ xr) * 8;         // swizzled element offset in row
      half8 af[4], bf[4];
#pragma unroll
      for (int i = 0; i < 4; i++)
        af[i] = *(const half8*)&As[(wr + i * 16 + fr) * 64 + so];
#pragma unroll
      for (int j = 0; j < 4; j++)
        bf[j] = *(const half8*)&Bs[(wc + j * 16 + fr) * 64 + so];
#pragma unroll
      for (int i = 0; i < 4; i++)
#pragma unroll
        for (int j = 0; j < 4; j++)
          acc[i][j] = __builtin_amdgcn_mfma_f32_16x16x32_f16(af[i], bf[j], acc[i][j], 0, 0, 0);
    }
  }
  const int rg = (lane >> 4) * 4;
#pragma unroll
  for (int i = 0; i < 4; i++) {
#pragma unroll
    for (int j = 0; j < 4; j++) {
      int col = bn + wc + j * 16 + fr;
#pragma unroll
      for (int r = 0; r < 4; r++) {
        int row = bm + wr + i * 16 + rg + r;
        float v = acc[i][j][r] * alpha;
        if (OUT_F32)
          ((float*)C)[z * strideC + (size_t)row * N + col] = v;
        else
          ((_Float16*)C)[z * strideC + (size_t)row * N + col] = (_Float16)v;
      }
    }
  }
}

// ---------------- block reduce helper (256 threads, 4 waves) ----------------
__device__ __forceinline__ float block_reduce(float v, bool do_max, float* wbuf, int tid) {
#pragma unroll
  for (int m = 32; m; m >>= 1) {
    float o = __shfl_xor(v, m);
    v = do_max ? fmaxf(v, o) : (v + o);
  }
  if ((tid & 63) == 0) wbuf[tid >> 6] = v;
  __syncthreads();
  float r = do_max ? fmaxf(fmaxf(wbuf[0], wbuf[1]), fmaxf(wbuf[2], wbuf[3]))
                   : (wbuf[0] + wbuf[1] + wbuf[2] + wbuf[3]);
  __syncthreads();
  return r;
}

// ---------------- pass 1: per-compact-row masked softmax stats -------------
// One block per kept S-row. stats_c[b*2048+r] = (rowmax, w/denom, 0, 0)
__global__ __launch_bounds__(256) void row_stats_kernel(
    const _Float16* __restrict__ S, const float* __restrict__ row_w,
    const int* __restrict__ keepM, const int* __restrict__ amask,
    float4* __restrict__ stats_c) {
  const int r = blockIdx.x;
  if (r >= *keepM) return;
  __shared__ float wbuf[4];
  const int b = blockIdx.z;
  const int tid = threadIdx.x;
  const float w = row_w[r];
  const _Float16* sp = S + ((size_t)b * 2048 + r) * 4096;
  const int* am = amask + (size_t)b * 4096;
  float a[16];
#pragma unroll
  for (int h = 0; h < 2; h++) {
    half8 v = *(const half8*)(sp + h * 2048 + tid * 8);
    int4 m0 = *(const int4*)(am + h * 2048 + tid * 8);
    int4 m1 = *(const int4*)(am + h * 2048 + tid * 8 + 4);
    int mm[8] = {m0.x, m0.y, m0.z, m0.w, m1.x, m1.y, m1.z, m1.w};
#pragma unroll
    for (int u = 0; u < 8; u++)
      a[h * 8 + u] = (mm[u] != 0) ? (float)v[u] : MASK_FILL;
  }
  float mx = a[0];
#pragma unroll
  for (int c = 1; c < 16; c++) mx = fmaxf(mx, a[c]);
  mx = block_reduce(mx, true, wbuf, tid);
  float ls = 0.f;
#pragma unroll
  for (int c = 0; c < 16; c++) ls += expf(a[c] - mx);
  float denom = block_reduce(ls, false, wbuf, tid);
  if (tid == 0)
    stats_c[(size_t)b * 2048 + r] = make_float4(mx, w / denom, 0.f, 0.f);
}

// ---------------- pass 2: ds-weighted combine over kept rows ---------------
// ca[b][kd][n] = sum_{i in [start[kd],start[kd+1])} iw * exp(a - mx)
// cnt==0 (nv==0 corner): uniform 1/4096.
__global__ __launch_bounds__(256) void combine_kernel(
    const _Float16* __restrict__ S, const float4* __restrict__ stats_c,
    const int* __restrict__ start, const int* __restrict__ amask,
    float* __restrict__ ca) {
  const int kd = blockIdx.x;
  const int b = blockIdx.z;
  const int n0 = blockIdx.y * 512 + threadIdx.x * 2;
  const int i0 = start[kd], i1 = start[kd + 1];
  float acc0, acc1;
  if (i0 == i1) {
    acc0 = acc1 = 1.0f / 4096.0f;
  } else {
    const int* am = amask + (size_t)b * 4096;
    const bool nm0 = am[n0] != 0, nm1 = am[n0 + 1] != 0;
    acc0 = 0.f;
    acc1 = 0.f;
    for (int i = i0; i < i1; i++) {
      float4 s4 = stats_c[(size_t)b * 2048 + i];
      half2v v = *(const half2v*)(S + ((size_t)b * 2048 + i) * 4096 + n0);
      float a0 = nm0 ? (float)v[0] : MASK_FILL;
      float a1 = nm1 ? (float)v[1] : MASK_FILL;
      acc0 += s4.y * expf(a0 - s4.x);
      acc1 += s4.y * expf(a1 - s4.x);
    }
  }
  float2 r = {acc0, acc1};
  *(float2*)&ca[((size_t)b * 64 + kd) * 4096 + n0] = r;
}

// ---------------- t partial: t[b*64+m][j] = sum_n ca[b][m][n] * x[b][n][j] ----
__global__ __launch_bounds__(256) void t_partial_kernel(
    const float* __restrict__ ca,   // [4][64][4096]
    const float* __restrict__ x,    // [4][4096][768]
    float* __restrict__ t_part) {   // [16][256][768]
  __shared__ float cas[64][68];
  __shared__ float xs[64][68];
  const int jt = blockIdx.x;  // 0..11
  const int nc = blockIdx.y;  // 0..15
  const int b = blockIdx.z;   // 0..3
  const int tid = threadIdx.x;
  const int tm = tid >> 4, tj = tid & 15;
  const int r = tid >> 2, cg = (tid & 3) * 16;
  float acc[4][4] = {};
  for (int n0 = nc * 256; n0 < nc * 256 + 256; n0 += 64) {
    __syncthreads();
    const float* cap = ca + ((size_t)(b * 64 + r)) * 4096 + n0 + cg;
    const float* xp = x + ((size_t)b * 4096 + n0 + r) * 768 + jt * 64 + cg;
#pragma unroll
    for (int u = 0; u < 16; u += 4) {
      *(float4*)&cas[r][cg + u] = *(const float4*)(cap + u);
      *(float4*)&xs[r][cg + u] = *(const float4*)(xp + u);
    }
    __syncthreads();
#pragma unroll 16
    for (int nn = 0; nn < 64; ++nn) {
      float cm[4], xj[4];
#pragma unroll
      for (int i = 0; i < 4; i++) cm[i] = cas[tm * 4 + i][nn];
#pragma unroll
      for (int j = 0; j < 4; j++) xj[j] = xs[nn][tj * 4 + j];
#pragma unroll
      for (int i = 0; i < 4; i++)
#pragma unroll
        for (int j = 0; j < 4; j++) acc[i][j] += cm[i] * xj[j];
    }
  }
#pragma unroll
  for (int i = 0; i < 4; i++)
#pragma unroll
    for (int j = 0; j < 4; j++)
      t_part[((size_t)nc * 256 + b * 64 + tm * 4 + i) * 768 + jt * 64 + tj * 4 + j] = acc[i][j];
}

__global__ __launch_bounds__(256) void t_reduce_kernel(
    const float* __restrict__ t_part, float* __restrict__ t) {
  int i = blockIdx.x * 256 + threadIdx.x;  // < 196608
  float s = 0.f;
#pragma unroll
  for (int nc = 0; nc < 16; ++nc) s += t_part[(size_t)nc * 196608 + i];
  t[i] = s;
}

// ---------------- LayerNorm + final projection ----------------
__global__ __launch_bounds__(256) void ln_out_kernel(
    const float* __restrict__ pooled, const float* __restrict__ Wo,
    const float* __restrict__ bo, const float* __restrict__ gamma,
    const float* __restrict__ beta, float* __restrict__ out) {
  __shared__ float wbuf[4];
  const int row = blockIdx.x, tid = threadIdx.x;
  float p[3];
#pragma unroll
  for (int u = 0; u < 3; u++) p[u] = pooled[(size_t)row * 768 + tid + u * 256];
  float s1 = p[0] + p[1] + p[2];
  float s2 = p[0] * p[0] + p[1] * p[1] + p[2] * p[2];
  s1 = block_reduce(s1, false, wbuf, tid);
  s2 = block_reduce(s2, false, wbuf, tid);
  float mean = s1 * (1.f / 768.f);
  float var = s2 * (1.f / 768.f) - mean * mean;
  float rstd = rsqrtf(var + LN_EPS);
  float accv = 0.f;
#pragma unroll
  for (int u = 0; u < 3; u++) {
    int i = tid + u * 256;
    float y = (p[u] - mean) * rstd * gamma[i] + beta[i];
    accv += y * Wo[i];
  }
  accv = block_reduce(accv, false, wbuf, tid);
  if (tid == 0) out[row] = accv + bo[0];
}

extern "C" void kernel_launch(void* const* d_in, const int* in_sizes, int n_in,
                              void* d_out, int out_size, void* d_ws, size_t ws_size,
                              hipStream_t stream) {
  const float* x = (const float*)d_in[0];
  const float* enc = (const float*)d_in[1];
  const int* dmask = (const int*)d_in[2];
  const int* amask = (const int*)d_in[3];
  const float* Wk = (const float*)d_in[4];
  const float* Wv = (const float*)d_in[5];
  const float* Wo = (const float*)d_in[6];
  const float* bo = (const float*)d_in[7];
  const float* gamma = (const float*)d_in[8];
  const float* beta = (const float*)d_in[9];
  float* out = (float*)d_out;

  char* ws = (char*)d_ws;
  size_t off = 0;
  auto alloc = [&](size_t bytes) -> char* {
    char* p = ws + off;
    off += (bytes + 255) & ~((size_t)255);
    return p;
  };
  _Float16* xh = (_Float16*)alloc((size_t)16384 * 768 * 2);
  _Float16* ench = (_Float16*)alloc((size_t)2048 * 768 * 2);
  _Float16* wkT = (_Float16*)alloc((size_t)768 * 768 * 2);
  _Float16* wvh = (_Float16*)alloc((size_t)768 * 768 * 2);
  _Float16* enc_c = (_Float16*)alloc((size_t)2048 * 768 * 2);
  _Float16* encK_c = (_Float16*)alloc((size_t)2048 * 768 * 2);
  float* ca = (float*)alloc((size_t)4 * 64 * 4096 * 4);
  float* t_part = (float*)alloc((size_t)16 * 256 * 768 * 4);
  float* t = (float*)alloc((size_t)256 * 768 * 4);
  _Float16* th = (_Float16*)alloc((size_t)256 * 768 * 2);
  float* pooled = (float*)alloc((size_t)256 * 768 * 4);
  float4* stats_c = (float4*)alloc((size_t)4 * 2048 * 16);
  int* rowmap = (int*)alloc(2048 * 4);
  float* row_w = (float*)alloc(2048 * 4);
  int* start = (int*)alloc(65 * 4);
  int* keepM = (int*)alloc(4);

  // batched path needs 4 S buffers (67.1 MB); fallback needs 1 (16.8 MB)
  const size_t s_one = (size_t)2048 * 4096 * 2;
  const bool batched = (off + 4 * s_one) <= ws_size;
  _Float16* S = (_Float16*)alloc(batched ? 4 * s_one : s_one);

  const float scale = 0.036084391824351615f;  // 1/sqrt(768)

  prep_kernel<<<1, 256, 0, stream>>>(dmask, rowmap, row_w, start, keepM);
  cast_f32_f16_kernel<<<12288, 256, 0, stream>>>(x, xh, 16384 * 768 / 4);
  cast_f32_f16_kernel<<<1536, 256, 0, stream>>>(enc, ench, 2048 * 768 / 4);
  cast_f32_f16_kernel<<<576, 256, 0, stream>>>(Wv, wvh, 768 * 768 / 4);
  transpose_f32_to_f16_kernel<<<dim3(24, 24), 256, 0, stream>>>(Wk, wkT, 768, 768);
  gather_rows_kernel<<<2048, 256, 0, stream>>>(ench, rowmap, keepM, enc_c);

  // encK_c = enc_c @ Wk   [keepM x 768]
  gemm_f16_kernel<false><<<dim3(16, 6), 256, 0, stream>>>(
      enc_c, wkT, encK_c, 2048, 768, 768, 1.0f, 0, 0, keepM);

  if (batched) {
    gemm_f16_kernel<false><<<dim3(16, 32, 4), 256, 0, stream>>>(
        encK_c, xh, S, 2048, 4096, 768, scale,
        (size_t)4096 * 768, (size_t)2048 * 4096, keepM);
    row_stats_kernel<<<dim3(2048, 1, 4), 256, 0, stream>>>(
        S, row_w, keepM, amask, stats_c);
    combine_kernel<<<dim3(64, 8, 4), 256, 0, stream>>>(S, stats_c, start, amask, ca);
  } else {
    for (int b = 0; b < 4; b++) {
      gemm_f16_kernel<false><<<dim3(16, 32), 256, 0, stream>>>(
          encK_c, xh + (size_t)b * 4096 * 768, S, 2048, 4096, 768, scale, 0, 0, keepM);
      row_stats_kernel<<<dim3(2048, 1, 1), 256, 0, stream>>>(
          S, row_w, keepM, amask + (size_t)b * 4096, stats_c + (size_t)b * 2048);
      combine_kernel<<<dim3(64, 8, 1), 256, 0, stream>>>(
          S, stats_c + (size_t)b * 2048, start, amask + (size_t)b * 4096,
          ca + (size_t)b * 64 * 4096);
    }
  }

  // t = ca @ x  (fp32), split over n-chunks then reduced
  t_partial_kernel<<<dim3(12, 16, 4), 256, 0, stream>>>(ca, x, t_part);
  t_reduce_kernel<<<768, 256, 0, stream>>>(t_part, t);
  cast_f32_f16_kernel<<<192, 256, 0, stream>>>(t, th, 196608 / 4);
  // pooled = t @ Wv^T  [256 x 768] fp32
  gemm_f16_kernel<true><<<dim3(2, 6), 256, 0, stream>>>(
      th, wvh, pooled, 256, 768, 768, 1.0f, 0, 0, nullptr);
  ln_out_kernel<<<256, 256, 0, stream>>>(pooled, Wo, bo, gamma, beta, out);
}

// Round 6
// 164.267 us; speedup vs baseline: 1.2896x; 1.1076x over previous
//
#include <hip/hip_runtime.h>
#include <hip/hip_bf16.h>
#include <hip/hip_fp16.h>

typedef _Float16 half8 __attribute__((ext_vector_type(8)));
typedef _Float16 half4 __attribute__((ext_vector_type(4)));
typedef _Float16 half2v __attribute__((ext_vector_type(2)));
typedef float f32x4 __attribute__((ext_vector_type(4)));

#define LN_EPS 1e-5f
#define MASK_FILL -1e9f

// async global->LDS, 16B per lane. LDS dest is wave-uniform base + lane*16.
__device__ __forceinline__ void async16(void* lds, const void* g) {
  __builtin_amdgcn_global_load_lds(
      (__attribute__((address_space(1))) void*)(g),
      (__attribute__((address_space(3))) void*)(lds), 16, 0, 0);
}

// ---------------- cast f32 -> f16 (vec4) ----------------
__global__ __launch_bounds__(256) void cast_f32_f16_kernel(
    const float* __restrict__ in, _Float16* __restrict__ out, int n4) {
  int i = blockIdx.x * 256 + threadIdx.x;
  if (i < n4) {
    float4 v = ((const float4*)in)[i];
    half4 h = { (_Float16)v.x, (_Float16)v.y, (_Float16)v.z, (_Float16)v.w };
    ((half4*)out)[i] = h;
  }
}

// ---------------- transpose f32 [R][C] -> f16 [C][R] ----------------
__global__ __launch_bounds__(256) void transpose_f32_to_f16_kernel(
    const float* __restrict__ in, _Float16* __restrict__ out, int R, int C) {
  __shared__ float tile[32][33];
  int bc = blockIdx.x * 32, br = blockIdx.y * 32;
  int lc = threadIdx.x & 31;
  int lr0 = threadIdx.x >> 5;  // 0..7
  for (int i = lr0; i < 32; i += 8)
    tile[i][lc] = in[(size_t)(br + i) * C + bc + lc];
  __syncthreads();
  for (int i = lr0; i < 32; i += 8)
    out[(size_t)(bc + i) * R + br + lc] = (_Float16)tile[lc][i];
}

// ---------------- prep: compact rows with dmask!=0 ----------------
// 1 block, 256 threads. Outputs: rowmap (compact->orig row), row_w (=1/nv(kd)),
// start[65] (per-kd compact range), keepM.
__global__ __launch_bounds__(256) void prep_kernel(
    const int* __restrict__ dmask, int* __restrict__ rowmap,
    float* __restrict__ row_w, int* __restrict__ start, int* __restrict__ keepM) {
  __shared__ int lsum[256];
  __shared__ int nvs[64];
  const int tid = threadIdx.x;
  int flags[8];
  int cnt = 0;
#pragma unroll
  for (int u = 0; u < 8; u++) {
    flags[u] = dmask[tid * 8 + u] != 0;
    cnt += flags[u];
  }
  if (tid < 64) {
    int c = 0;
    for (int u = 0; u < 32; u++) c += (dmask[tid * 32 + u] != 0);
    nvs[tid] = c;
  }
  lsum[tid] = cnt;
  __syncthreads();
  for (int ofs = 1; ofs < 256; ofs <<= 1) {
    int t = (tid >= ofs) ? lsum[tid - ofs] : 0;
    __syncthreads();
    lsum[tid] += t;
    __syncthreads();
  }
  int excl = lsum[tid] - cnt;
  int pos = excl;
#pragma unroll
  for (int u = 0; u < 8; u++) {
    if (flags[u]) {
      int row = tid * 8 + u;
      rowmap[pos] = row;
      row_w[pos] = 1.0f / (float)nvs[row >> 5];
      pos++;
    }
  }
  if ((tid & 3) == 0) start[tid >> 2] = excl;
  if (tid == 255) {
    start[64] = lsum[255];
    *keepM = lsum[255];
  }
}

// ---------------- gather+cast kept rows of enc (f32 [2048][768]) -> f16 ----
// dst[r] = (f16)src[rowmap[r]] for r < keepM, else zeros (pad for GEMM tiles).
__global__ __launch_bounds__(256) void gather_cast_kernel(
    const float* __restrict__ src, const int* __restrict__ rowmap,
    const int* __restrict__ keepM, _Float16* __restrict__ dst) {
  const int r = blockIdx.x;
  const int t = threadIdx.x;
  const int k = *keepM;
  _Float16* d = dst + (size_t)r * 768;
  if (r < k) {
    const float* s = src + (size_t)rowmap[r] * 768;
    for (int i = t; i < 768; i += 256) d[i] = (_Float16)s[i];
  } else {
    int* di = (int*)d;
    for (int i = t; i < 384; i += 256) di[i] = 0;
  }
}

// ---------------- fp16 MFMA GEMM, m97 structure, BK=64, XOR-swizzled LDS ---
// C[M][N] = alpha * A[M][K] @ Bt[N][K]^T. 128x128 tile, BK=64, 4 waves (2x2),
// each wave 64x64 via 4x4 16x16x32 frags x2 k-subtiles.
// LDS layout: LDS[row][slot] = orig[row][slot ^ (row&7)] (16B granules, 8/row)
// via pre-swizzled per-lane GLOBAL src (LDS dest linear, as gload_lds needs).
// XCD=true: bijective chunked blockIdx swizzle so the 16 M-blocks sharing one
// B-panel land on ONE XCD (L2 locality). Requires total blocks % 8 == 0.
template<bool OUT_F32, bool XCD>
__global__ __launch_bounds__(256) void gemm_f16_kernel(
    const _Float16* __restrict__ A, const _Float16* __restrict__ Bt,
    void* __restrict__ C, int M, int N, int K, float alpha,
    size_t strideBt, size_t strideC, const int* __restrict__ keepRows) {
  int bx = blockIdx.x, by = blockIdx.y, bz = blockIdx.z;
  if (XCD) {
    const int gx = gridDim.x, gy = gridDim.y;
    const int total = gx * gy * gridDim.z;
    const int L = bx + gx * (by + gy * bz);
    const int orig = (L & 7) * (total >> 3) + (L >> 3);
    bx = orig % gx;
    const int rest = orig / gx;
    by = rest % gy;
    bz = rest / gy;
  }
  const int bm = bx * 128, bn = by * 128;
  if (keepRows && bm >= *keepRows) return;
  __shared__ _Float16 As[128 * 64];
  __shared__ _Float16 Bs[128 * 64];
  const int tid = threadIdx.x;
  const size_t z = bz;
  const int wave = tid >> 6, lane = tid & 63;
  const int wr = (wave >> 1) * 64, wc = (wave & 1) * 64;
  const int fr = lane & 15, xr = lane & 7;  // xr = (frag row)&7 for all i,j
  f32x4 acc[4][4] = {};
  // staging: wave w covers rows [w*32, w*32+32); one issue = 8 rows of 128B.
  // lane l -> row (l>>3), LDS slot (l&7); global granule = (l&7)^(l>>3).
  const int srow = wave * 32 + (lane >> 3);
  const int scol = (((lane & 7) ^ (lane >> 3))) * 8;  // elems
  const _Float16* ga = A + (size_t)(bm + srow) * K + scol;
  const _Float16* gb = Bt + z * strideBt + (size_t)(bn + srow) * K + scol;
  _Float16* lA = &As[(wave * 32) * 64];
  _Float16* lB = &Bs[(wave * 32) * 64];
  for (int k0 = 0; k0 < K; k0 += 64) {
    __syncthreads();  // all waves done reading LDS from previous iter
#pragma unroll
    for (int i = 0; i < 4; i++) {
      async16(lA + i * 8 * 64, ga + (size_t)(8 * i) * K + k0);
      async16(lB + i * 8 * 64, gb + (size_t)(8 * i) * K + k0);
    }
    __syncthreads();  // drains vmcnt(0): staging complete
#pragma unroll
    for (int k2 = 0; k2 < 2; k2++) {
      const int sb = k2 * 4 + (lane >> 4);  // unswizzled slot this lane needs
      const int so = (sb ^ xr) * 8;         // swizzled element offset in row
      half8 af[4], bf[4];
#pragma unroll
      for (int i = 0; i < 4; i++)
        af[i] = *(const half8*)&As[(wr + i * 16 + fr) * 64 + so];
#pragma unroll
      for (int j = 0; j < 4; j++)
        bf[j] = *(const half8*)&Bs[(wc + j * 16 + fr) * 64 + so];
#pragma unroll
      for (int i = 0; i < 4; i++)
#pragma unroll
        for (int j = 0; j < 4; j++)
          acc[i][j] = __builtin_amdgcn_mfma_f32_16x16x32_f16(af[i], bf[j], acc[i][j], 0, 0, 0);
    }
  }
  const int rg = (lane >> 4) * 4;
#pragma unroll
  for (int i = 0; i < 4; i++) {
#pragma unroll
    for (int j = 0; j < 4; j++) {
      int col = bn + wc + j * 16 + fr;
#pragma unroll
      for (int r = 0; r < 4; r++) {
        int row = bm + wr + i * 16 + rg + r;
        float v = acc[i][j][r] * alpha;
        if (OUT_F32)
          ((float*)C)[z * strideC + (size_t)row * N + col] = v;
        else
          ((_Float16*)C)[z * strideC + (size_t)row * N + col] = (_Float16)v;
      }
    }
  }
}

// ---------------- block reduce helper (256 threads, 4 waves) ----------------
__device__ __forceinline__ float block_reduce(float v, bool do_max, float* wbuf, int tid) {
#pragma unroll
  for (int m = 32; m; m >>= 1) {
    float o = __shfl_xor(v, m);
    v = do_max ? fmaxf(v, o) : (v + o);
  }
  if ((tid & 63) == 0) wbuf[tid >> 6] = v;
  __syncthreads();
  float r = do_max ? fmaxf(fmaxf(wbuf[0], wbuf[1]), fmaxf(wbuf[2], wbuf[3]))
                   : (wbuf[0] + wbuf[1] + wbuf[2] + wbuf[3]);
  __syncthreads();
  return r;
}

// ---------------- pass 1: per-compact-row masked softmax stats -------------
// One block per kept S-row. stats_c[b*2048+r] = (rowmax, w/denom, 0, 0)
__global__ __launch_bounds__(256) void row_stats_kernel(
    const _Float16* __restrict__ S, const float* __restrict__ row_w,
    const int* __restrict__ keepM, const int* __restrict__ amask,
    float4* __restrict__ stats_c) {
  const int r = blockIdx.x;
  if (r >= *keepM) return;
  __shared__ float wbuf[4];
  const int b = blockIdx.z;
  const int tid = threadIdx.x;
  const float w = row_w[r];
  const _Float16* sp = S + ((size_t)b * 2048 + r) * 4096;
  const int* am = amask + (size_t)b * 4096;
  float a[16];
#pragma unroll
  for (int h = 0; h < 2; h++) {
    half8 v = *(const half8*)(sp + h * 2048 + tid * 8);
    int4 m0 = *(const int4*)(am + h * 2048 + tid * 8);
    int4 m1 = *(const int4*)(am + h * 2048 + tid * 8 + 4);
    int mm[8] = {m0.x, m0.y, m0.z, m0.w, m1.x, m1.y, m1.z, m1.w};
#pragma unroll
    for (int u = 0; u < 8; u++)
      a[h * 8 + u] = (mm[u] != 0) ? (float)v[u] : MASK_FILL;
  }
  float mx = a[0];
#pragma unroll
  for (int c = 1; c < 16; c++) mx = fmaxf(mx, a[c]);
  mx = block_reduce(mx, true, wbuf, tid);
  float ls = 0.f;
#pragma unroll
  for (int c = 0; c < 16; c++) ls += expf(a[c] - mx);
  float denom = block_reduce(ls, false, wbuf, tid);
  if (tid == 0)
    stats_c[(size_t)b * 2048 + r] = make_float4(mx, w / denom, 0.f, 0.f);
}

// ---------------- pass 2: ds-weighted combine over kept rows ---------------
// ca[b][kd][n] = sum_{i in [start[kd],start[kd+1])} iw * exp(a - mx)
// cnt==0 (nv==0 corner): uniform 1/4096.
__global__ __launch_bounds__(256) void combine_kernel(
    const _Float16* __restrict__ S, const float4* __restrict__ stats_c,
    const int* __restrict__ start, const int* __restrict__ amask,
    float* __restrict__ ca) {
  const int kd = blockIdx.x;
  const int b = blockIdx.z;
  const int n0 = blockIdx.y * 512 + threadIdx.x * 2;
  const int i0 = start[kd], i1 = start[kd + 1];
  float acc0, acc1;
  if (i0 == i1) {
    acc0 = acc1 = 1.0f / 4096.0f;
  } else {
    const int* am = amask + (size_t)b * 4096;
    const bool nm0 = am[n0] != 0, nm1 = am[n0 + 1] != 0;
    acc0 = 0.f;
    acc1 = 0.f;
    for (int i = i0; i < i1; i++) {
      float4 s4 = stats_c[(size_t)b * 2048 + i];
      half2v v = *(const half2v*)(S + ((size_t)b * 2048 + i) * 4096 + n0);
      float a0 = nm0 ? (float)v[0] : MASK_FILL;
      float a1 = nm1 ? (float)v[1] : MASK_FILL;
      acc0 += s4.y * expf(a0 - s4.x);
      acc1 += s4.y * expf(a1 - s4.x);
    }
  }
  float2 r = {acc0, acc1};
  *(float2*)&ca[((size_t)b * 64 + kd) * 4096 + n0] = r;
}

// ---------------- t partial: t[b*64+m][j] = sum_n ca[b][m][n] * xh[b][n][j] --
// j-tile = 128 (ca re-read 6x instead of 12x); x read as f16 (half traffic).
__global__ __launch_bounds__(256) void t_partial_kernel(
    const float* __restrict__ ca,     // [4][64][4096]
    const _Float16* __restrict__ xh,  // [4][4096][768] f16
    float* __restrict__ t_part) {     // [16][256][768]
  __shared__ float cas[64][68];
  __shared__ float xs[64][132];
  const int jt = blockIdx.x;  // 0..5
  const int nc = blockIdx.y;  // 0..15
  const int b = blockIdx.z;   // 0..3
  const int tid = threadIdx.x;
  const int tm = tid >> 4, tj = tid & 15;
  const int r = tid >> 2;
  const int cg = (tid & 3) * 16;  // cas cols
  const int cc = (tid & 3) * 32;  // xs cols
  float acc[4][8] = {};
  for (int n0 = nc * 256; n0 < nc * 256 + 256; n0 += 64) {
    __syncthreads();
    const float* cap = ca + (size_t)(b * 64 + r) * 4096 + n0 + cg;
#pragma unroll
    for (int u = 0; u < 16; u += 4)
      *(float4*)&cas[r][cg + u] = *(const float4*)(cap + u);
    const _Float16* xp = xh + ((size_t)b * 4096 + n0 + r) * 768 + jt * 128 + cc;
#pragma unroll
    for (int u = 0; u < 32; u += 8) {
      half8 hv = *(const half8*)(xp + u);
#pragma unroll
      for (int q = 0; q < 8; q++) xs[r][cc + u + q] = (float)hv[q];
    }
    __syncthreads();
#pragma unroll 8
    for (int nn = 0; nn < 64; ++nn) {
      float cm[4], xj[8];
#pragma unroll
      for (int i = 0; i < 4; i++) cm[i] = cas[tm * 4 + i][nn];
#pragma unroll
      for (int j = 0; j < 8; j++) xj[j] = xs[nn][tj * 8 + j];
#pragma unroll
      for (int i = 0; i < 4; i++)
#pragma unroll
        for (int j = 0; j < 8; j++) acc[i][j] += cm[i] * xj[j];
    }
  }
#pragma unroll
  for (int i = 0; i < 4; i++)
#pragma unroll
    for (int j = 0; j < 8; j++)
      t_part[((size_t)nc * 256 + b * 64 + tm * 4 + i) * 768 + jt * 128 + tj * 8 + j] = acc[i][j];
}

// reduce partials and cast to f16 for the pooled GEMM
__global__ __launch_bounds__(256) void t_reduce_kernel(
    const float* __restrict__ t_part, _Float16* __restrict__ th) {
  int i = blockIdx.x * 256 + threadIdx.x;  // < 196608
  float s = 0.f;
#pragma unroll
  for (int nc = 0; nc < 16; ++nc) s += t_part[(size_t)nc * 196608 + i];
  th[i] = (_Float16)s;
}

// ---------------- LayerNorm + final projection ----------------
__global__ __launch_bounds__(256) void ln_out_kernel(
    const float* __restrict__ pooled, const float* __restrict__ Wo,
    const float* __restrict__ bo, const float* __restrict__ gamma,
    const float* __restrict__ beta, float* __restrict__ out) {
  __shared__ float wbuf[4];
  const int row = blockIdx.x, tid = threadIdx.x;
  float p[3];
#pragma unroll
  for (int u = 0; u < 3; u++) p[u] = pooled[(size_t)row * 768 + tid + u * 256];
  float s1 = p[0] + p[1] + p[2];
  float s2 = p[0] * p[0] + p[1] * p[1] + p[2] * p[2];
  s1 = block_reduce(s1, false, wbuf, tid);
  s2 = block_reduce(s2, false, wbuf, tid);
  float mean = s1 * (1.f / 768.f);
  float var = s2 * (1.f / 768.f) - mean * mean;
  float rstd = rsqrtf(var + LN_EPS);
  float accv = 0.f;
#pragma unroll
  for (int u = 0; u < 3; u++) {
    int i = tid + u * 256;
    float y = (p[u] - mean) * rstd * gamma[i] + beta[i];
    accv += y * Wo[i];
  }
  accv = block_reduce(accv, false, wbuf, tid);
  if (tid == 0) out[row] = accv + bo[0];
}

extern "C" void kernel_launch(void* const* d_in, const int* in_sizes, int n_in,
                              void* d_out, int out_size, void* d_ws, size_t ws_size,
                              hipStream_t stream) {
  const float* x = (const float*)d_in[0];
  const float* enc = (const float*)d_in[1];
  const int* dmask = (const int*)d_in[2];
  const int* amask = (const int*)d_in[3];
  const float* Wk = (const float*)d_in[4];
  const float* Wv = (const float*)d_in[5];
  const float* Wo = (const float*)d_in[6];
  const float* bo = (const float*)d_in[7];
  const float* gamma = (const float*)d_in[8];
  const float* beta = (const float*)d_in[9];
  float* out = (float*)d_out;

  char* ws = (char*)d_ws;
  size_t off = 0;
  auto alloc = [&](size_t bytes) -> char* {
    char* p = ws + off;
    off += (bytes + 255) & ~((size_t)255);
    return p;
  };
  _Float16* xh = (_Float16*)alloc((size_t)16384 * 768 * 2);
  _Float16* wkT = (_Float16*)alloc((size_t)768 * 768 * 2);
  _Float16* wvh = (_Float16*)alloc((size_t)768 * 768 * 2);
  _Float16* enc_c = (_Float16*)alloc((size_t)2048 * 768 * 2);
  _Float16* encK_c = (_Float16*)alloc((size_t)2048 * 768 * 2);
  float* ca = (float*)alloc((size_t)4 * 64 * 4096 * 4);
  float* t_part = (float*)alloc((size_t)16 * 256 * 768 * 4);
  _Float16* th = (_Float16*)alloc((size_t)256 * 768 * 2);
  float* pooled = (float*)alloc((size_t)256 * 768 * 4);
  float4* stats_c = (float4*)alloc((size_t)4 * 2048 * 16);
  int* rowmap = (int*)alloc(2048 * 4);
  float* row_w = (float*)alloc(2048 * 4);
  int* start = (int*)alloc(65 * 4);
  int* keepM = (int*)alloc(4);

  // batched path needs 4 S buffers (67.1 MB); fallback needs 1 (16.8 MB)
  const size_t s_one = (size_t)2048 * 4096 * 2;
  const bool batched = (off + 4 * s_one) <= ws_size;
  _Float16* S = (_Float16*)alloc(batched ? 4 * s_one : s_one);

  const float scale = 0.036084391824351615f;  // 1/sqrt(768)

  prep_kernel<<<1, 256, 0, stream>>>(dmask, rowmap, row_w, start, keepM);
  cast_f32_f16_kernel<<<12288, 256, 0, stream>>>(x, xh, 16384 * 768 / 4);
  cast_f32_f16_kernel<<<576, 256, 0, stream>>>(Wv, wvh, 768 * 768 / 4);
  transpose_f32_to_f16_kernel<<<dim3(24, 24), 256, 0, stream>>>(Wk, wkT, 768, 768);
  gather_cast_kernel<<<2048, 256, 0, stream>>>(enc, rowmap, keepM, enc_c);

  // encK_c = enc_c @ Wk   [keepM x 768]
  gemm_f16_kernel<false, false><<<dim3(16, 6), 256, 0, stream>>>(
      enc_c, wkT, encK_c, 2048, 768, 768, 1.0f, 0, 0, keepM);

  if (batched) {
    gemm_f16_kernel<false, true><<<dim3(16, 32, 4), 256, 0, stream>>>(
        encK_c, xh, S, 2048, 4096, 768, scale,
        (size_t)4096 * 768, (size_t)2048 * 4096, keepM);
    row_stats_kernel<<<dim3(2048, 1, 4), 256, 0, stream>>>(
        S, row_w, keepM, amask, stats_c);
    combine_kernel<<<dim3(64, 8, 4), 256, 0, stream>>>(S, stats_c, start, amask, ca);
  } else {
    for (int b = 0; b < 4; b++) {
      gemm_f16_kernel<false, true><<<dim3(16, 32), 256, 0, stream>>>(
          encK_c, xh + (size_t)b * 4096 * 768, S, 2048, 4096, 768, scale, 0, 0, keepM);
      row_stats_kernel<<<dim3(2048, 1, 1), 256, 0, stream>>>(
          S, row_w, keepM, amask + (size_t)b * 4096, stats_c + (size_t)b * 2048);
      combine_kernel<<<dim3(64, 8, 1), 256, 0, stream>>>(
          S, stats_c + (size_t)b * 2048, start, amask + (size_t)b * 4096,
          ca + (size_t)b * 64 * 4096);
    }
  }

  // t = ca @ xh  (fp32 accum), split over n-chunks then reduced to f16
  t_partial_kernel<<<dim3(6, 16, 4), 256, 0, stream>>>(ca, xh, t_part);
  t_reduce_kernel<<<768, 256, 0, stream>>>(t_part, th);
  // pooled = t @ Wv^T  [256 x 768] fp32
  gemm_f16_kernel<true, false><<<dim3(2, 6), 256, 0, stream>>>(
      th, wvh, pooled, 256, 768, 768, 1.0f, 0, 0, nullptr);
  ln_out_kernel<<<256, 256, 0, stream>>>(pooled, Wo, bo, gamma, beta, out);
}